// Round 4
// baseline (443.263 us; speedup 1.0000x reference)
//
#include <hip/hip_runtime.h>
#include <hip/hip_bf16.h>

#define NUM_AA    20
#define NUM_PAIRS 400
#define DD        64
#define NT        512   // threads per block
#define NW        8     // waves per block
#define BPW       50    // buckets per wave (contiguous)
#define LMAX      2048
#define MAXC      20    // padded member-table depth (overflow -> fallback path)
#define SENT      0xFFFFu

// One block per (b, t). Counting-sort positions by pair-bucket, then a
// slot-major gather: each wave owns 50 contiguous buckets with register
// accumulators acc[50]; sweep m = member-slot, issuing up to 100 independent
// branchless global loads per sweep (sentinel-masked). Kills the per-bucket
// pipeline drain that bounded round 3 at ~330 cyc/member.
__global__ __launch_bounds__(NT, 4)
void cksaap_kernel(const int* __restrict__ seq,
                   const float* __restrict__ emb,
                   float* __restrict__ out,
                   int B, int L, int k)
{
    __shared__ int            s_seq[LMAX];            // 8 KB
    __shared__ unsigned short s_idx[LMAX];            // 4 KB
    __shared__ unsigned short s_ord[LMAX];            // 4 KB
    __shared__ unsigned short s_pad[NUM_PAIRS * MAXC];// 16 KB padded member table
    __shared__ int            s_cnt[NUM_PAIRS];       // 1.6 KB
    __shared__ int            s_off[NUM_PAIRS];       // 1.6 KB
    __shared__ int            s_cur[NUM_PAIRS];       // 1.6 KB
    __shared__ int            s_scan[NT];             // 2 KB

    const int T   = k + 1;
    const int nwg = gridDim.x;
    const int i   = blockIdx.x;
    int b, t;
    if (nwg == 1024 && T == 4) {
        // XCD-aware: 4 t-blocks of one b land on the same XCD
        const int x = i & 7;
        const int s = i >> 3;
        t = s >> 5;
        b = x * 32 + (s & 31);
    } else {
        b = i / T; t = i % T;
    }

    const int tid  = threadIdx.x;
    const int lane = tid & 63;
    const int wave = tid >> 6;
    const int n    = L - t - 1;

    // phase 1: stage seq row, zero counts
    for (int j = tid; j < L; j += NT) s_seq[j] = seq[(size_t)b * L + j];
    if (tid < NUM_PAIRS) s_cnt[tid] = 0;
    __syncthreads();

    // phase 2: bucket per position + counts
    for (int j = tid; j < n; j += NT) {
        const int idx = s_seq[j] * NUM_AA + s_seq[j + t + 1];
        s_idx[j] = (unsigned short)idx;
        atomicAdd(&s_cnt[idx], 1);
    }
    __syncthreads();

    // phase 3: exclusive prefix scan (Hillis-Steele over 512)
    const int c0 = (tid < NUM_PAIRS) ? s_cnt[tid] : 0;
    s_scan[tid] = c0;
    __syncthreads();
    for (int off = 1; off < NT; off <<= 1) {
        int v = s_scan[tid];
        if (tid >= off) v += s_scan[tid - off];
        __syncthreads();
        s_scan[tid] = v;
        __syncthreads();
    }
    if (tid < NUM_PAIRS) {
        const int excl = s_scan[tid] - c0;
        s_off[tid] = excl;
        s_cur[tid] = excl;
    }
    __syncthreads();

    // phase 4: scatter position ids into bucket-sorted order
    for (int j = tid; j < n; j += NT) {
        const int idx = s_idx[j];
        const int r   = atomicAdd(&s_cur[idx], 1);
        s_ord[r] = (unsigned short)j;
    }
    __syncthreads();

    // phase 4.5: build padded member table (sentinel-filled)
    for (int e = tid; e < NUM_PAIRS * MAXC; e += NT) {
        const int p = e / MAXC;
        const int m = e - p * MAXC;
        const int c = s_cnt[p];
        s_pad[e] = (m < c) ? s_ord[s_off[p] + m] : (unsigned short)SENT;
    }
    __syncthreads();

    // phase 5: slot-major register gather
    const float  scale = 0.5f / (float)n;
    const float* embb  = emb + (size_t)b * L * DD;
    float*       outp  = out + ((size_t)b * T + t) * (size_t)(NUM_PAIRS * DD);
    const int    p0    = wave * BPW;
    const int    gap   = (t + 1) * DD;

    // per-wave max member count (capped at MAXC)
    int c = (lane < BPW) ? s_cnt[p0 + lane] : 0;
    #pragma unroll
    for (int o = 32; o > 0; o >>= 1) c = max(c, __shfl_xor(c, o));
    const int maxm = min(c, MAXC);

    float acc[BPW];
    #pragma unroll
    for (int q = 0; q < BPW; ++q) acc[q] = 0.0f;

    for (int m = 0; m < maxm; ++m) {
        #pragma unroll
        for (int q = 0; q < BPW; ++q) {
            const unsigned int j = s_pad[(p0 + q) * MAXC + m];
            const int   jv = (j == SENT) ? 0 : (int)j;          // safe address
            const float w  = (j == SENT) ? 0.0f : 1.0f;         // mask weight
            const float a  = embb[(size_t)jv * DD + lane];
            const float bb = embb[(size_t)jv * DD + gap + lane];
            acc[q] += w * (a + bb);
        }
    }

    // overflow fallback (cnt > MAXC): essentially never taken, keeps correctness
    #pragma unroll 1
    for (int q = 0; q < BPW; ++q) {
        const int cc = s_cnt[p0 + q];
        if (cc > MAXC) {
            const int base = s_off[p0 + q];
            for (int m = MAXC; m < cc; ++m) {
                const int j = s_ord[base + m];
                acc[q] += embb[(size_t)j * DD + lane] +
                          embb[(size_t)j * DD + gap + lane];
            }
        }
    }

    // store
    #pragma unroll
    for (int q = 0; q < BPW; ++q) {
        outp[(size_t)(p0 + q) * DD + lane] = acc[q] * scale;
    }
}

extern "C" void kernel_launch(void* const* d_in, const int* in_sizes, int n_in,
                              void* d_out, int out_size, void* d_ws, size_t ws_size,
                              hipStream_t stream)
{
    const int*   seq = (const int*)d_in[0];
    const float* emb = (const float*)d_in[1];
    float*       out = (float*)d_out;

    const int B = 256;
    const int L = in_sizes[0] / B;                        // 2048
    const int k = out_size / (B * NUM_PAIRS * DD) - 1;    // 3

    cksaap_kernel<<<B * (k + 1), NT, 0, stream>>>(seq, emb, out, B, L, k);
}

// Round 5
// 323.196 us; speedup vs baseline: 1.3715x; 1.3715x over previous
//
#include <hip/hip_runtime.h>
#include <hip/hip_bf16.h>

#define NUM_AA    20
#define NUM_PAIRS 400
#define DD        64
#define NT        512   // threads per block
#define NW        8     // waves per block
#define GB        8     // buckets per gather-group (register accumulators)
#define LMAX      2048

// One block per (b, t). Counting-sort positions by pair-bucket; then sort the
// 400 buckets by member-count (descending, counting sort over 64 clamped
// bins); gather in groups of GB=8 near-equal-count buckets with register
// accumulators and 16 independent masked loads per sweep. No scratch, no
// per-bucket pipeline drain, no padding waste.
__global__ __launch_bounds__(NT, 4)
void cksaap_kernel(const int* __restrict__ seq,
                   const float* __restrict__ emb,
                   float* __restrict__ out,
                   int B, int L, int k)
{
    __shared__ int            s_seq[LMAX];       // 8 KB
    __shared__ unsigned short s_idx[LMAX];       // 4 KB
    __shared__ unsigned short s_ord[LMAX];       // 4 KB positions sorted by bucket
    __shared__ unsigned short s_bkt[NUM_PAIRS];  // 0.8 KB bucket ids sorted by count desc
    __shared__ int            s_cnt[NUM_PAIRS];  // 1.6 KB
    __shared__ int            s_off[NUM_PAIRS];  // 1.6 KB
    __shared__ int            s_cur[NUM_PAIRS];  // 1.6 KB
    __shared__ int            s_scan[NT];        // 2 KB
    __shared__ int            s_chist[64];       // count histogram (clamped bins)
    __shared__ int            s_coff[64];        // descending-order cursors

    const int T   = k + 1;
    const int nwg = gridDim.x;
    const int i   = blockIdx.x;
    int b, t;
    if (nwg == 1024 && T == 4) {
        // XCD-aware: 4 t-blocks of one b land on the same XCD for emb L2 reuse
        const int x = i & 7;
        const int s = i >> 3;
        t = s >> 5;
        b = x * 32 + (s & 31);
    } else {
        b = i / T; t = i % T;
    }

    const int tid  = threadIdx.x;
    const int lane = tid & 63;
    const int wave = tid >> 6;
    const int n    = L - t - 1;

    // phase 1: stage seq row, zero counters
    for (int j = tid; j < L; j += NT) s_seq[j] = seq[(size_t)b * L + j];
    if (tid < NUM_PAIRS) s_cnt[tid] = 0;
    if (tid < 64) s_chist[tid] = 0;
    __syncthreads();

    // phase 2: bucket per position + counts
    for (int j = tid; j < n; j += NT) {
        const int idx = s_seq[j] * NUM_AA + s_seq[j + t + 1];
        s_idx[j] = (unsigned short)idx;
        atomicAdd(&s_cnt[idx], 1);
    }
    __syncthreads();

    // phase 3: exclusive prefix scan of bucket counts (Hillis-Steele)
    const int c0 = (tid < NUM_PAIRS) ? s_cnt[tid] : 0;
    s_scan[tid] = c0;
    __syncthreads();
    for (int off = 1; off < NT; off <<= 1) {
        int v = s_scan[tid];
        if (tid >= off) v += s_scan[tid - off];
        __syncthreads();
        s_scan[tid] = v;
        __syncthreads();
    }
    if (tid < NUM_PAIRS) {
        const int excl = s_scan[tid] - c0;
        s_off[tid] = excl;
        s_cur[tid] = excl;
    }
    // histogram of (clamped) counts for the bucket-by-count sort
    if (tid < NUM_PAIRS) atomicAdd(&s_chist[min(c0, 63)], 1);
    __syncthreads();

    // phase 4: scatter position ids into bucket-sorted order
    for (int j = tid; j < n; j += NT) {
        const int idx = s_idx[j];
        const int r   = atomicAdd(&s_cur[idx], 1);
        s_ord[r] = (unsigned short)j;
    }
    // phase 4.5a: descending offsets for count bins (suffix sums, 64 lanes)
    if (tid < 64) {
        int s = 0;
        for (int c2 = tid + 1; c2 < 64; ++c2) s += s_chist[c2];
        s_coff[tid] = s;
    }
    __syncthreads();
    // phase 4.5b: scatter bucket ids into count-descending order
    if (tid < NUM_PAIRS) {
        const int r = atomicAdd(&s_coff[min(s_cnt[tid], 63)], 1);
        s_bkt[r] = (unsigned short)tid;
    }
    __syncthreads();

    // phase 5: group-major register gather (GB buckets of similar count)
    const float  scale = 0.5f / (float)n;
    const float* embb  = emb + (size_t)b * L * DD;
    float*       outp  = out + ((size_t)b * T + t) * (size_t)(NUM_PAIRS * DD);
    const int    gap   = (t + 1) * DD;
    const int    ngroups = NUM_PAIRS / GB;   // 50

    for (int g = wave; g < ngroups; g += NW) {
        const int r0 = g * GB;
        int pid[GB], cc[GB], off[GB];
        #pragma unroll
        for (int q = 0; q < GB; ++q) {
            pid[q] = s_bkt[r0 + q];
            cc[q]  = s_cnt[pid[q]];
            off[q] = s_off[pid[q]];
        }
        int gmax = 0;
        #pragma unroll
        for (int q = 0; q < GB; ++q) gmax = max(gmax, cc[q]);

        float acc[GB];
        #pragma unroll
        for (int q = 0; q < GB; ++q) acc[q] = 0.0f;

        for (int m = 0; m < gmax; ++m) {
            #pragma unroll
            for (int q = 0; q < GB; ++q) {
                const bool  ok = (m < cc[q]);
                const int   j  = ok ? (int)s_ord[off[q] + m] : 0;
                const float w  = ok ? 1.0f : 0.0f;
                const float a  = embb[(size_t)j * DD + lane];
                const float bb = embb[(size_t)j * DD + gap + lane];
                acc[q] += w * (a + bb);
            }
        }

        #pragma unroll
        for (int q = 0; q < GB; ++q) {
            outp[(size_t)pid[q] * DD + lane] = acc[q] * scale;
        }
    }
}

extern "C" void kernel_launch(void* const* d_in, const int* in_sizes, int n_in,
                              void* d_out, int out_size, void* d_ws, size_t ws_size,
                              hipStream_t stream)
{
    const int*   seq = (const int*)d_in[0];
    const float* emb = (const float*)d_in[1];
    float*       out = (float*)d_out;

    const int B = 256;
    const int L = in_sizes[0] / B;                        // 2048
    const int k = out_size / (B * NUM_PAIRS * DD) - 1;    // 3

    cksaap_kernel<<<B * (k + 1), NT, 0, stream>>>(seq, emb, out, B, L, k);
}